// Round 8
// baseline (321.242 us; speedup 1.0000x reference)
//
#include <hip/hip_runtime.h>
#include <hip/hip_bf16.h>

// ---- problem constants ----
#define GF    7
#define TAPS  25
#define NCHNK 7          // K chunks; f-major ordering: chunk ck <-> f = ck
#define NTILE 10         // tiles of 6 output rows
#define TROWS 6
#define SROWS 10         // 6 + 4 halo
#define NPOS  360        // 6*60 positions per tile
#define NF_   23         // ceil(360/16); frag 22 has 8 valid lanes
#define NGRP  35         // NCHNK * 5 kh-groups

typedef __attribute__((ext_vector_type(8)))  __bf16 bf16x8;
typedef __attribute__((ext_vector_type(8)))  unsigned short u16x8;
typedef __attribute__((ext_vector_type(4)))  float f32x4;

__device__ __forceinline__ f32x4 mfma16(u16x8 a, u16x8 b, f32x4 c) {
  return __builtin_amdgcn_mfma_f32_16x16x32_bf16(
      __builtin_bit_cast(bf16x8, a), __builtin_bit_cast(bf16x8, b), c, 0, 0, 0);
}

// async global->LDS, 16B/lane; dest = wave-uniform base, HW adds lane*16
__device__ __forceinline__ void glds16(const unsigned short* g, unsigned short* l) {
  __builtin_amdgcn_global_load_lds(
      (__attribute__((address_space(1))) void*)g,
      (__attribute__((address_space(3))) void*)l, 16, 0, 0);
}

// w[o][c][f][kh][kw] f32 -> wt[tap][ck=f][o][slot][e] bf16, swizzle baked:
// slot s holds logical channel-octet oct = s ^ ((o>>1)&3); channel c = 8*oct+e.
__global__ void wt_kernel(const float* __restrict__ w, unsigned short* __restrict__ wt) {
  int i = blockIdx.x * 256 + threadIdx.x;
  if (i >= TAPS * NCHNK * 64 * 32) return;
  int e   = i & 7;
  int s   = (i >> 3) & 3;
  int o   = (i >> 5) & 63;
  int ck  = (i >> 11) % NCHNK;
  int tap = i / (NCHNK * 64 * 32);
  int oct = s ^ ((o >> 1) & 3);
  int c   = 8 * oct + e;
  float v = w[((size_t)(o * 32 + c) * GF + ck) * TAPS + tap];
  __bf16 hb = (__bf16)v;
  wt[i] = __builtin_bit_cast(unsigned short, hb);
}

// x[b][c][gin][4096] f32 -> xt[b*33+gin][pos][32ch] bf16 with the Xs bank
// swizzle baked into the global layout: octet oct stored at slot oct^((pos>>1)&3).
// Staging in conv is then a LINEAR 40KB global_load_lds copy (rule 21 pattern).
__global__ void xt_kernel(const float* __restrict__ x, unsigned short* __restrict__ xt) {
  int blk = blockIdx.x;            // 264 planes * 64 rows
  int row = blk & 63;
  int pl  = blk >> 6;              // b*33 + gin
  int tid = threadIdx.x;
  int col = tid >> 2, oct = tid & 3;
  int b = pl / 33, gin = pl - 33 * b;
  const float* xp = x + (((size_t)b * 32 * 33 + gin) << 12) + row * 64 + col;
  u16x8 pk;
#pragma unroll
  for (int e = 0; e < 8; ++e) {
    float v = xp[(size_t)(8 * oct + e) * 135168];   // c-plane stride 33*4096
    pk[e] = __builtin_bit_cast(unsigned short, (__bf16)v);
  }
  int pos = row * 64 + col;
  *reinterpret_cast<u16x8*>(
      &xt[((size_t)pl << 17) + pos * 32 + 8 * (oct ^ ((pos >> 1) & 3))]) = pk;
}

// Block = (b, g, 6-row tile). 4 waves; wave = 4m(16 o) x <=6n(16 pos), 16x16x32.
// Dynamic LDS 81920B: Xs 40KB @0, Ws double-buffer 2x20KB @20480/@30720 (u16).
// All staging via global_load_lds. One raw barrier per group; Ws prefetch
// distance = 1 full group (counted-vmcnt, T4); Xs swap drains only 6x/block.
__global__ void __launch_bounds__(256, 2)
conv_kernel(const unsigned short* __restrict__ xt, const unsigned short* __restrict__ wt,
            const float* __restrict__ bias, const int* __restrict__ idx,
            float* __restrict__ out) {
  extern __shared__ __align__(16) unsigned short lds[];

  // XCD-aware bijective swizzle: 1200 = 8 * 150
  const int bid0 = blockIdx.x;
  const int bid  = (bid0 & 7) * 150 + (bid0 >> 3);
  const int tile = bid % NTILE;
  const int g    = (bid / NTILE) % 15;
  const int b    = bid / (NTILE * 15);

  const int tid  = threadIdx.x;
  const int lane = tid & 63;
  const int wv   = tid >> 6;
  const int lo   = lane & 15;
  const int lk   = lane >> 4;
  const int r0   = tile * TROWS;

  // group-gather plane ids (uniform; loaded BEFORE the vmcnt ledger starts)
  int g7[NCHNK];
#pragma unroll
  for (int f = 0; f < NCHNK; ++f) g7[f] = idx[g * GF + f];
  asm volatile("s_waitcnt vmcnt(0) lgkmcnt(0)" ::: "memory");

  auto issue_ws = [&](int gi) {   // 5 glds16/wave -> Ws buf[gi&1]
    const int ckp = gi / 5, khp = gi - 5 * (gi / 5);
    unsigned short* dst = lds + 20480 + (gi & 1) * 10240;
#pragma unroll
    for (int t = 0; t < 5; ++t)
      glds16(wt + (((khp * 5 + t) * NCHNK + ckp) << 11) + tid * 8,
             dst + t * 2048 + wv * 512);
  };
  auto issue_xs = [&](int ckp) {  // 10 glds16/wave -> Xs (linear 40KB)
    const unsigned short* src =
        xt + (((size_t)(b * 33 + g7[ckp])) << 17) + r0 * 2048 + wv * 5120 + lane * 8;
#pragma unroll
    for (int t = 0; t < 10; ++t)
      glds16(src + t * 512, lds + wv * 5120 + t * 512);
  };

  issue_ws(0);
  issue_xs(0);
  issue_ws(1);

  // n-frag bases: wave owns frags {wv, wv+4, ...} -> (6,6,6,5) balanced
  int p0[6];
  int pvalid = 0;
#pragma unroll
  for (int i = 0; i < 6; ++i) {
    int nf = wv + 4 * i;
    p0[i] = 0;
    if (nf < NF_) {
      int p  = nf * 16 + lo;
      int pc = (p < NPOS) ? p : 0;
      int ph = pc / 60;
      p0[i] = ph * 64 + (pc - 60 * ph);
      pvalid = i + 1;
    }
  }
  // A-read swizzled offsets (kw-invariant)
  int aoff[4];
#pragma unroll
  for (int m = 0; m < 4; ++m)
    aoff[m] = (m * 16 + lo) * 32 + 8 * (lk ^ ((lo >> 1) & 3));

  f32x4 acc[4][6];
#pragma unroll
  for (int m = 0; m < 4; ++m)
#pragma unroll
    for (int i = 0; i < 6; ++i) acc[m][i] = f32x4{0.f, 0.f, 0.f, 0.f};

  asm volatile("s_waitcnt vmcnt(5)" ::: "memory");  // W(0)+Xs(0) landed; W(1) in flight
  __builtin_amdgcn_s_barrier();

#pragma unroll 1
  for (int gi = 0; gi < NGRP; ++gi) {
    const int ck = gi / 5, kh = gi - 5 * (gi / 5);
    const unsigned short* Wcur = lds + 20480 + (gi & 1) * 10240;

#pragma unroll
    for (int kw = 0; kw < 5; ++kw) {
      u16x8 a[4], bf[6];
#pragma unroll
      for (int m = 0; m < 4; ++m)
        a[m] = *reinterpret_cast<const u16x8*>(&Wcur[kw * 2048 + aoff[m]]);
      const int toff = kh * 64 + kw;
#pragma unroll
      for (int i = 0; i < 6; ++i)
        if (i < pvalid) {
          int pt = p0[i] + toff;
          bf[i] = *reinterpret_cast<const u16x8*>(
              &lds[pt * 32 + 8 * (lk ^ ((pt >> 1) & 3))]);
        }
      __builtin_amdgcn_s_setprio(1);
#pragma unroll
      for (int i = 0; i < 6; ++i)
        if (i < pvalid)
#pragma unroll
          for (int m = 0; m < 4; ++m)
            acc[m][i] = mfma16(a[m], bf[i], acc[m][i]);
      __builtin_amdgcn_s_setprio(0);
    }

    if (gi == NGRP - 1) break;
    if (kh == 4) {
      // chunk swap: drain, publish, restage Xs + W(gi+2), short exposed wait
      asm volatile("s_waitcnt vmcnt(0)" ::: "memory");
      __builtin_amdgcn_s_barrier();
      issue_xs(ck + 1);
      issue_ws(gi + 2);
      asm volatile("s_waitcnt vmcnt(5)" ::: "memory");  // Xs done; W(gi+2) in flight
      __builtin_amdgcn_s_barrier();
    } else {
      asm volatile("s_waitcnt vmcnt(0)" ::: "memory");  // own W(gi+1) (overlapped)
      __builtin_amdgcn_s_barrier();
      if (gi + 2 < NGRP) issue_ws(gi + 2);              // into buf just freed
    }
  }

  // bias into registers: o = m*16 + 4*lk + v
  float bv[4][4];
#pragma unroll
  for (int m = 0; m < 4; ++m)
#pragma unroll
    for (int v = 0; v < 4; ++v) bv[m][v] = bias[m * 16 + 4 * lk + v];

  // epilogue: out[((b*64+o)*15+g)*3600 + tile*360 + p]
#pragma unroll
  for (int i = 0; i < 6; ++i) {
    if (i < pvalid) {
      int nf = wv + 4 * i;
      int p  = nf * 16 + lo;
      if (p < NPOS) {
        const size_t pb = (size_t)tile * NPOS + p;
#pragma unroll
        for (int m = 0; m < 4; ++m)
#pragma unroll
          for (int v = 0; v < 4; ++v) {
            int o = m * 16 + 4 * lk + v;
            out[((size_t)(b * 64 + o) * 15 + g) * 3600 + pb] = acc[m][i][v] + bv[m][v];
          }
      }
    }
  }
}

extern "C" void kernel_launch(void* const* d_in, const int* in_sizes, int n_in,
                              void* d_out, int out_size, void* d_ws, size_t ws_size,
                              hipStream_t stream) {
  const float* x      = (const float*)d_in[0];
  const float* weight = (const float*)d_in[1];
  const float* bias   = (const float*)d_in[2];
  const int*   idx    = (const int*)d_in[3];
  float* out = (float*)d_out;
  unsigned short* wt = (unsigned short*)d_ws;            // 716800 B
  unsigned short* xt = (unsigned short*)d_ws + 358400;   // 264*131072 u16 = 69.2 MB

  (void)hipFuncSetAttribute(reinterpret_cast<const void*>(conv_kernel),
                            hipFuncAttributeMaxDynamicSharedMemorySize, 81920);

  wt_kernel<<<(TAPS * NCHNK * 64 * 32 + 255) / 256, 256, 0, stream>>>(weight, wt);
  xt_kernel<<<264 * 64, 256, 0, stream>>>(x, xt);
  conv_kernel<<<8 * 15 * NTILE, 256, 81920, stream>>>(xt, wt, bias, idx, out);
}

// Round 9
// 298.319 us; speedup vs baseline: 1.0768x; 1.0768x over previous
//
#include <hip/hip_runtime.h>
#include <hip/hip_bf16.h>

// ---- problem constants ----
#define GF    7
#define TAPS  25
#define NCHNK 7          // K chunks; f-major: chunk ck <-> f = ck
#define NTILE 10         // tiles of 6 output rows
#define TROWS 6
#define SROWS 10         // 6 + 4 halo
#define NPOS  360        // 6*60 positions per tile
#define NF_   23         // ceil(360/16); frag 22 has 8 valid lanes
#define NGRP  35         // NCHNK * 5 kh-groups

typedef __attribute__((ext_vector_type(8)))  __bf16 bf16x8;
typedef __attribute__((ext_vector_type(8)))  unsigned short u16x8;
typedef __attribute__((ext_vector_type(4)))  float f32x4;

__device__ __forceinline__ f32x4 mfma16(u16x8 a, u16x8 b, f32x4 c) {
  return __builtin_amdgcn_mfma_f32_16x16x32_bf16(
      __builtin_bit_cast(bf16x8, a), __builtin_bit_cast(bf16x8, b), c, 0, 0, 0);
}

// async global->LDS, 16B/lane; dest = wave-uniform base, HW adds lane*16
__device__ __forceinline__ void glds16(const unsigned short* g, unsigned short* l) {
  __builtin_amdgcn_global_load_lds(
      (__attribute__((address_space(1))) void*)g,
      (__attribute__((address_space(3))) void*)l, 16, 0, 0);
}

// w[o][c][f][kh][kw] f32 -> wt[tap][ck=f][o][c] bf16, LINEAR (no swizzle:
// staging is DMA-linear and the A-read bank pattern is slot-permutation-
// invariant, so swizzle only cost VALU).
__global__ void wt_kernel(const float* __restrict__ w, unsigned short* __restrict__ wt) {
  int i = blockIdx.x * 256 + threadIdx.x;
  if (i >= TAPS * NCHNK * 64 * 32) return;
  int c   = i & 31;
  int o   = (i >> 5) & 63;
  int ck  = (i >> 11) % NCHNK;
  int tap = i / (NCHNK * 64 * 32);
  float v = w[((size_t)(o * 32 + c) * GF + ck) * TAPS + tap];
  __bf16 hb = (__bf16)v;
  wt[i] = __builtin_bit_cast(unsigned short, hb);
}

// x[b][c][gin][4096] f32 -> xt[b*33+gin][pos][32ch] bf16, LINEAR.
__global__ void xt_kernel(const float* __restrict__ x, unsigned short* __restrict__ xt) {
  int blk = blockIdx.x;            // 264 planes * 64 rows
  int row = blk & 63;
  int pl  = blk >> 6;              // b*33 + gin
  int tid = threadIdx.x;
  int col = tid >> 2, oct = tid & 3;
  int b = pl / 33, gin = pl - 33 * b;
  const float* xp = x + (((size_t)b * 32 * 33 + gin) << 12) + row * 64 + col;
  u16x8 pk;
#pragma unroll
  for (int e = 0; e < 8; ++e) {
    float v = xp[(size_t)(8 * oct + e) * 135168];   // c-plane stride 33*4096
    pk[e] = __builtin_bit_cast(unsigned short, (__bf16)v);
  }
  int pos = row * 64 + col;
  *reinterpret_cast<u16x8*>(&xt[((size_t)pl << 17) + pos * 32 + 8 * oct]) = pk;
}

// Block = (b, g, 6-row tile). 4 waves; wave = 4m(16 o) x <=6n(16 pos), 16x16x32.
// Dynamic LDS 81920B: Xs 40KB @0 (u16 idx 0..20479), Ws 2x20KB @20480/@30720.
// All staging via global_load_lds (linear). kh fully unrolled inside the ck
// loop -> every inner LDS read is base-vreg + assembler immediate: the K-loop
// has ZERO address VALU. Ledger identical to r8 (counted vmcnt, 1-group
// prefetch distance for Ws; Xs swap drains 6x/block).
__global__ void __launch_bounds__(256, 2)
conv_kernel(const unsigned short* __restrict__ xt, const unsigned short* __restrict__ wt,
            const float* __restrict__ bias, const int* __restrict__ idx,
            float* __restrict__ out) {
  extern __shared__ __align__(16) unsigned short lds[];

  // XCD-aware bijective swizzle: 1200 = 8 * 150
  const int bid0 = blockIdx.x;
  const int bid  = (bid0 & 7) * 150 + (bid0 >> 3);
  const int tile = bid % NTILE;
  const int g    = (bid / NTILE) % 15;
  const int b    = bid / (NTILE * 15);

  const int tid  = threadIdx.x;
  const int lane = tid & 63;
  const int wv   = tid >> 6;
  const int lo   = lane & 15;
  const int lk   = lane >> 4;
  const int r0   = tile * TROWS;

  // group-gather plane ids (uniform; loaded BEFORE the vmcnt ledger starts)
  int g7[NCHNK];
#pragma unroll
  for (int f = 0; f < NCHNK; ++f) g7[f] = idx[g * GF + f];
  asm volatile("s_waitcnt vmcnt(0) lgkmcnt(0)" ::: "memory");

  auto issue_ws = [&](int gi) {   // 5 glds16/wave -> Ws buf[gi&1]
    const int ckp = gi / 5, khp = gi - 5 * (gi / 5);
    unsigned short* dst = lds + 20480 + (gi & 1) * 10240;
#pragma unroll
    for (int t = 0; t < 5; ++t)
      glds16(wt + (((khp * 5 + t) * NCHNK + ckp) << 11) + tid * 8,
             dst + t * 2048 + wv * 512);
  };
  auto issue_xs = [&](int ckp) {  // 10 glds16/wave -> Xs (linear 40KB)
    const unsigned short* src =
        xt + (((size_t)(b * 33 + g7[ckp])) << 17) + r0 * 2048 + wv * 5120 + lane * 8;
#pragma unroll
    for (int t = 0; t < 10; ++t)
      glds16(src + t * 512, lds + wv * 5120 + t * 512);
  };

  issue_ws(0);
  issue_xs(0);
  issue_ws(1);

  // n-frag bases: wave owns frags {wv, wv+4, ...} -> (6,6,6,5) balanced.
  // pbyte[i]: u16 index of this lane's B-frag at tap (0,0); taps add a
  // compile-time immediate (kh*64+kw)*32.
  int pbyte[6];
  int pvalid = 0;
#pragma unroll
  for (int i = 0; i < 6; ++i) {
    int nf = wv + 4 * i;
    pbyte[i] = 8 * lk;
    if (nf < NF_) {
      int p  = nf * 16 + lo;
      int pc = (p < NPOS) ? p : 0;
      int ph = pc / 60;
      pbyte[i] = (ph * 64 + (pc - 60 * ph)) * 32 + 8 * lk;
      pvalid = i + 1;
    }
  }
  // A-read bases (kw adds immediate kw*2048)
  int abase[4];
#pragma unroll
  for (int m = 0; m < 4; ++m) abase[m] = (m * 16 + lo) * 32 + 8 * lk;

  f32x4 acc[4][6];
#pragma unroll
  for (int m = 0; m < 4; ++m)
#pragma unroll
    for (int i = 0; i < 6; ++i) acc[m][i] = f32x4{0.f, 0.f, 0.f, 0.f};

  asm volatile("s_waitcnt vmcnt(5)" ::: "memory");  // W(0)+Xs(0) landed; W(1) in flight
  __builtin_amdgcn_s_barrier();

#pragma unroll 1
  for (int ck = 0; ck < NCHNK; ++ck) {
#pragma unroll
    for (int kh = 0; kh < 5; ++kh) {
      const int gi = ck * 5 + kh;
      const unsigned short* Wcur = lds + 20480 + (gi & 1) * 10240;

#pragma unroll
      for (int kw = 0; kw < 5; ++kw) {
        u16x8 a[4], bf[6];
#pragma unroll
        for (int m = 0; m < 4; ++m)
          a[m] = *reinterpret_cast<const u16x8*>(&Wcur[kw * 2048 + abase[m]]);
#pragma unroll
        for (int i = 0; i < 6; ++i)
          if (i < pvalid)
            bf[i] = *reinterpret_cast<const u16x8*>(
                &lds[pbyte[i] + (kh * 64 + kw) * 32]);
        __builtin_amdgcn_s_setprio(1);
#pragma unroll
        for (int i = 0; i < 6; ++i)
          if (i < pvalid)
#pragma unroll
            for (int m = 0; m < 4; ++m)
              acc[m][i] = mfma16(a[m], bf[i], acc[m][i]);
        __builtin_amdgcn_s_setprio(0);
      }

      if (gi == NGRP - 1) break;
      if (kh == 4) {
        // chunk swap: drain, publish, restage Xs + W(gi+2), short exposed wait
        asm volatile("s_waitcnt vmcnt(0)" ::: "memory");
        __builtin_amdgcn_s_barrier();
        issue_xs(ck + 1);
        issue_ws(gi + 2);
        asm volatile("s_waitcnt vmcnt(5)" ::: "memory");  // Xs landed; W(gi+2) in flight
        __builtin_amdgcn_s_barrier();
      } else {
        asm volatile("s_waitcnt vmcnt(0)" ::: "memory");  // own W(gi+1) (overlapped)
        __builtin_amdgcn_s_barrier();
        if (gi + 2 < NGRP) issue_ws(gi + 2);              // into buf just freed
      }
    }
  }

  // bias into registers: o = m*16 + 4*lk + v
  float bv[4][4];
#pragma unroll
  for (int m = 0; m < 4; ++m)
#pragma unroll
    for (int v = 0; v < 4; ++v) bv[m][v] = bias[m * 16 + 4 * lk + v];

  // epilogue: out[((b*64+o)*15+g)*3600 + tile*360 + p]
#pragma unroll
  for (int i = 0; i < 6; ++i) {
    if (i < pvalid) {
      int nf = wv + 4 * i;
      int p  = nf * 16 + lo;
      if (p < NPOS) {
        const size_t pb = (size_t)tile * NPOS + p;
#pragma unroll
        for (int m = 0; m < 4; ++m)
#pragma unroll
          for (int v = 0; v < 4; ++v) {
            int o = m * 16 + 4 * lk + v;
            out[((size_t)(b * 64 + o) * 15 + g) * 3600 + pb] = acc[m][i][v] + bv[m][v];
          }
      }
    }
  }
}

extern "C" void kernel_launch(void* const* d_in, const int* in_sizes, int n_in,
                              void* d_out, int out_size, void* d_ws, size_t ws_size,
                              hipStream_t stream) {
  const float* x      = (const float*)d_in[0];
  const float* weight = (const float*)d_in[1];
  const float* bias   = (const float*)d_in[2];
  const int*   idx    = (const int*)d_in[3];
  float* out = (float*)d_out;
  unsigned short* wt = (unsigned short*)d_ws;            // 716800 B
  unsigned short* xt = (unsigned short*)d_ws + 358400;   // 264*131072 u16 = 69.2 MB

  (void)hipFuncSetAttribute(reinterpret_cast<const void*>(conv_kernel),
                            hipFuncAttributeMaxDynamicSharedMemorySize, 81920);

  wt_kernel<<<(TAPS * NCHNK * 64 * 32 + 255) / 256, 256, 0, stream>>>(weight, wt);
  xt_kernel<<<264 * 64, 256, 0, stream>>>(x, xt);
  conv_kernel<<<8 * 15 * NTILE, 256, 81920, stream>>>(xt, wt, bias, idx, out);
}

// Round 10
// 290.339 us; speedup vs baseline: 1.1064x; 1.0275x over previous
//
#include <hip/hip_runtime.h>
#include <hip/hip_bf16.h>

// ---- problem constants ----
#define GF    7
#define TAPS  25
#define NCHNK 7          // K chunks; f-major: chunk ck <-> f = ck
#define NTILE 10         // tiles of 6 output rows
#define TROWS 6
#define SROWS 10         // 6 + 4 halo
#define NPOS  360        // 6*60 positions per tile
#define NF_   23         // ceil(360/16); frag 22 has 8 valid lanes
#define NGRP  35         // NCHNK * 5 kh-groups

typedef __attribute__((ext_vector_type(8)))  __bf16 bf16x8;
typedef __attribute__((ext_vector_type(8)))  unsigned short u16x8;
typedef __attribute__((ext_vector_type(4)))  float f32x4;

__device__ __forceinline__ f32x4 mfma16(u16x8 a, u16x8 b, f32x4 c) {
  return __builtin_amdgcn_mfma_f32_16x16x32_bf16(
      __builtin_bit_cast(bf16x8, a), __builtin_bit_cast(bf16x8, b), c, 0, 0, 0);
}

// async global->LDS, 16B/lane; dest = wave-uniform base, HW adds lane*16
__device__ __forceinline__ void glds16(const unsigned short* g, unsigned short* l) {
  __builtin_amdgcn_global_load_lds(
      (__attribute__((address_space(1))) void*)g,
      (__attribute__((address_space(3))) void*)l, 16, 0, 0);
}

// w[o][c][f][kh][kw] f32 -> wt[tap][ck=f][o][slot][e] bf16, swizzle BAKED:
// slot s holds channel-octet oct = s ^ ((o>>1)&3)  (A-read 2-way max).
__global__ void wt_kernel(const float* __restrict__ w, unsigned short* __restrict__ wt) {
  int i = blockIdx.x * 256 + threadIdx.x;
  if (i >= TAPS * NCHNK * 64 * 32) return;
  int e   = i & 7;
  int s   = (i >> 3) & 3;
  int o   = (i >> 5) & 63;
  int ck  = (i >> 11) % NCHNK;
  int tap = i / (NCHNK * 64 * 32);
  int oct = s ^ ((o >> 1) & 3);
  int c   = 8 * oct + e;
  float v = w[((size_t)(o * 32 + c) * GF + ck) * TAPS + tap];
  __bf16 hb = (__bf16)v;
  wt[i] = __builtin_bit_cast(unsigned short, hb);
}

// x[b][c][gin][4096] f32 -> xt[b*33+gin][pos][32ch] bf16, swizzle BAKED:
// octet oct stored at slot oct ^ ((pos>>1)&3)  (B-read 2-way max).
__global__ void xt_kernel(const float* __restrict__ x, unsigned short* __restrict__ xt) {
  int blk = blockIdx.x;            // 264 planes * 64 rows
  int row = blk & 63;
  int pl  = blk >> 6;              // b*33 + gin
  int tid = threadIdx.x;
  int col = tid >> 2, oct = tid & 3;
  int b = pl / 33, gin = pl - 33 * b;
  const float* xp = x + (((size_t)b * 32 * 33 + gin) << 12) + row * 64 + col;
  u16x8 pk;
#pragma unroll
  for (int e = 0; e < 8; ++e) {
    float v = xp[(size_t)(8 * oct + e) * 135168];   // c-plane stride 33*4096
    pk[e] = __builtin_bit_cast(unsigned short, (__bf16)v);
  }
  int pos = row * 64 + col;
  *reinterpret_cast<u16x8*>(
      &xt[((size_t)pl << 17) + pos * 32 + 8 * (oct ^ ((pos >> 1) & 3))]) = pk;
}

// Block = (b, g, 6-row tile). 4 waves; wave = 4m(16 o) x <=6n(16 pos), 16x16x32.
// Dynamic LDS 81920B: Xs 40KB @0, Ws 2x20KB @20480/@30720 (u16 idx).
// All staging via global_load_lds (linear dest, swizzle pre-baked in global
// layout = rule-21 pattern). Inner K-loop: zero address VALU -- A offsets are
// tap-invariant (aoff), B offsets precomputed per kw (pb5, kh-invariant since
// kh*64 == 0 mod 8), kh/kw folds into ds_read immediates. Ledger as r8/r9.
__global__ void __launch_bounds__(256, 2)
conv_kernel(const unsigned short* __restrict__ xt, const unsigned short* __restrict__ wt,
            const float* __restrict__ bias, const int* __restrict__ idx,
            float* __restrict__ out) {
  extern __shared__ __align__(16) unsigned short lds[];

  // XCD-aware bijective swizzle: 1200 = 8 * 150
  const int bid0 = blockIdx.x;
  const int bid  = (bid0 & 7) * 150 + (bid0 >> 3);
  const int tile = bid % NTILE;
  const int g    = (bid / NTILE) % 15;
  const int b    = bid / (NTILE * 15);

  const int tid  = threadIdx.x;
  const int lane = tid & 63;
  const int wv   = tid >> 6;
  const int lo   = lane & 15;
  const int lk   = lane >> 4;
  const int r0   = tile * TROWS;

  // group-gather plane ids (uniform; loaded BEFORE the vmcnt ledger starts)
  int g7[NCHNK];
#pragma unroll
  for (int f = 0; f < NCHNK; ++f) g7[f] = idx[g * GF + f];
  asm volatile("s_waitcnt vmcnt(0) lgkmcnt(0)" ::: "memory");

  auto issue_ws = [&](int gi) {   // 5 glds16/wave -> Ws buf[gi&1]
    const int ckp = gi / 5, khp = gi - 5 * (gi / 5);
    unsigned short* dst = lds + 20480 + (gi & 1) * 10240;
#pragma unroll
    for (int t = 0; t < 5; ++t)
      glds16(wt + (((khp * 5 + t) * NCHNK + ckp) << 11) + tid * 8,
             dst + t * 2048 + wv * 512);
  };
  auto issue_xs = [&](int ckp) {  // 10 glds16/wave -> Xs (linear 40KB)
    const unsigned short* src =
        xt + (((size_t)(b * 33 + g7[ckp])) << 17) + r0 * 2048 + wv * 5120 + lane * 8;
#pragma unroll
    for (int t = 0; t < 10; ++t)
      glds16(src + t * 512, lds + wv * 5120 + t * 512);
  };

  issue_ws(0);
  issue_xs(0);
  issue_ws(1);

  // n-frag bases: wave owns frags {wv, wv+4, ...} -> (6,6,6,5) balanced.
  // pb5[i][kw]: u16 index of this lane's B-frag at (kh=0, kw); per-tap read =
  // pb5[i][kw] + kh*2048 (immediate). Swizzle (pt>>1)&3 is kh-invariant.
  int pb5[6][5];
  int pvalid = 0;
#pragma unroll
  for (int i = 0; i < 6; ++i) {
    int nf = wv + 4 * i;
#pragma unroll
    for (int kw = 0; kw < 5; ++kw) pb5[i][kw] = 8 * lk;
    if (nf < NF_) {
      int p  = nf * 16 + lo;
      int pc = (p < NPOS) ? p : 0;
      int ph = pc / 60;
      int pos0 = ph * 64 + (pc - 60 * ph);
#pragma unroll
      for (int kw = 0; kw < 5; ++kw) {
        int ptk = pos0 + kw;
        pb5[i][kw] = ptk * 32 + 8 * (lk ^ ((ptk >> 1) & 3));
      }
      pvalid = i + 1;
    }
  }
  // A-read offsets (tap-invariant; kw adds immediate kw*2048)
  int aoff[4];
#pragma unroll
  for (int m = 0; m < 4; ++m)
    aoff[m] = (m * 16 + lo) * 32 + 8 * (lk ^ ((lo >> 1) & 3));

  f32x4 acc[4][6];
#pragma unroll
  for (int m = 0; m < 4; ++m)
#pragma unroll
    for (int i = 0; i < 6; ++i) acc[m][i] = f32x4{0.f, 0.f, 0.f, 0.f};

  asm volatile("s_waitcnt vmcnt(5)" ::: "memory");  // W(0)+Xs(0) landed; W(1) in flight
  __builtin_amdgcn_s_barrier();

#pragma unroll 1
  for (int ck = 0; ck < NCHNK; ++ck) {
#pragma unroll
    for (int kh = 0; kh < 5; ++kh) {
      const int gi = ck * 5 + kh;
      const unsigned short* Wcur = lds + 20480 + (gi & 1) * 10240;

#pragma unroll
      for (int kw = 0; kw < 5; ++kw) {
        u16x8 a[4], bf[6];
#pragma unroll
        for (int m = 0; m < 4; ++m)
          a[m] = *reinterpret_cast<const u16x8*>(&Wcur[kw * 2048 + aoff[m]]);
#pragma unroll
        for (int i = 0; i < 6; ++i)
          if (i < pvalid)
            bf[i] = *reinterpret_cast<const u16x8*>(&lds[pb5[i][kw] + kh * 2048]);
        __builtin_amdgcn_s_setprio(1);
#pragma unroll
        for (int i = 0; i < 6; ++i)
          if (i < pvalid)
#pragma unroll
            for (int m = 0; m < 4; ++m)
              acc[m][i] = mfma16(a[m], bf[i], acc[m][i]);
        __builtin_amdgcn_s_setprio(0);
      }

      if (gi == NGRP - 1) break;
      if (kh == 4) {
        // chunk swap: drain, publish, restage Xs + W(gi+2), short exposed wait
        asm volatile("s_waitcnt vmcnt(0)" ::: "memory");
        __builtin_amdgcn_s_barrier();
        issue_xs(ck + 1);
        issue_ws(gi + 2);
        asm volatile("s_waitcnt vmcnt(5)" ::: "memory");  // Xs landed; W(gi+2) in flight
        __builtin_amdgcn_s_barrier();
      } else {
        asm volatile("s_waitcnt vmcnt(0)" ::: "memory");  // own W(gi+1) (overlapped)
        __builtin_amdgcn_s_barrier();
        if (gi + 2 < NGRP) issue_ws(gi + 2);              // into buf just freed
      }
    }
  }

  // bias into registers: o = m*16 + 4*lk + v
  float bv[4][4];
#pragma unroll
  for (int m = 0; m < 4; ++m)
#pragma unroll
    for (int v = 0; v < 4; ++v) bv[m][v] = bias[m * 16 + 4 * lk + v];

  // epilogue: out[((b*64+o)*15+g)*3600 + tile*360 + p]
#pragma unroll
  for (int i = 0; i < 6; ++i) {
    if (i < pvalid) {
      int nf = wv + 4 * i;
      int p  = nf * 16 + lo;
      if (p < NPOS) {
        const size_t pb = (size_t)tile * NPOS + p;
#pragma unroll
        for (int m = 0; m < 4; ++m)
#pragma unroll
          for (int v = 0; v < 4; ++v) {
            int o = m * 16 + 4 * lk + v;
            out[((size_t)(b * 64 + o) * 15 + g) * 3600 + pb] = acc[m][i][v] + bv[m][v];
          }
      }
    }
  }
}

extern "C" void kernel_launch(void* const* d_in, const int* in_sizes, int n_in,
                              void* d_out, int out_size, void* d_ws, size_t ws_size,
                              hipStream_t stream) {
  const float* x      = (const float*)d_in[0];
  const float* weight = (const float*)d_in[1];
  const float* bias   = (const float*)d_in[2];
  const int*   idx    = (const int*)d_in[3];
  float* out = (float*)d_out;
  unsigned short* wt = (unsigned short*)d_ws;            // 716800 B
  unsigned short* xt = (unsigned short*)d_ws + 358400;   // 264*131072 u16 = 69.2 MB

  (void)hipFuncSetAttribute(reinterpret_cast<const void*>(conv_kernel),
                            hipFuncAttributeMaxDynamicSharedMemorySize, 81920);

  wt_kernel<<<(TAPS * NCHNK * 64 * 32 + 255) / 256, 256, 0, stream>>>(weight, wt);
  xt_kernel<<<264 * 64, 256, 0, stream>>>(x, xt);
  conv_kernel<<<8 * 15 * NTILE, 256, 81920, stream>>>(xt, wt, bias, idx, out);
}